// Round 6
// baseline (191.774 us; speedup 1.0000x reference)
//
#include <hip/hip_runtime.h>
#include <hip/hip_bf16.h>
#include <math.h>

#define NBATCH 32
#define IMGSZ  224
#define NR     400
#define NA     1024
#define ED     96
#define SROW   266   // s_samp row stride in elems (256 cols + 10; odd dword)

typedef __attribute__((ext_vector_type(8))) __bf16 bf16x8;
typedef __attribute__((ext_vector_type(8), aligned(8))) __bf16 bf16x8u;
typedef __attribute__((ext_vector_type(4), aligned(8))) __bf16 bf16x4a;
typedef __attribute__((ext_vector_type(4))) __bf16 bf16x4;
typedef __attribute__((ext_vector_type(4))) float f32x4;

union frag_u { struct { bf16x4a lo, hi; } p; bf16x8 v; };

// ---------------------------------------------------------------------------
// ws layout (13.3 MB total — proven capacity, RD experiment reverted: it cut
// mega only 1.4 us but cost prep ~6 us):
//   rtab    f32 [32][400]
//   costab  f32 [1024]  (pre-scaled by 223/224)
//   sintab  f32 [1024]  (pre-scaled by 223/224)
//   w2f     bf16 [20*3*6][64][8]  fragment-major w2, j ^ ((ka+icb)&1)*4
//   w1f     bf16 [12][64][8]      fragment-major w1 (grp = ks*6+ot), k>=60 -> 0
//   xp      bf16 [32][224][224][4] channels-last packed image
// ---------------------------------------------------------------------------

#define PACK_N   (NBATCH*IMGSZ*IMGSZ)
#define PACK_N4  (PACK_N/4)               // 401408, exact
#define PACK_B   ((PACK_N4 + 255)/256)    // 1568, exact
#define PREP_N   (ED*ED*20 + 12*64*8 + NBATCH*NR + NA + NBATCH)
#define PREP_B   ((PREP_N + 255)/256)

// merged image pack (4 px/thread, float4 loads) + tables + weight reorder
__global__ __launch_bounds__(256)
void prep_pack_kernel(const float* __restrict__ x,
                      const float* __restrict__ dist,
                      const float* __restrict__ w1,
                      const float* __restrict__ w2,
                      __bf16* __restrict__ xp,
                      float* __restrict__ rtab,
                      float* __restrict__ costab,
                      float* __restrict__ sintab,
                      __bf16* __restrict__ w2f,
                      __bf16* __restrict__ w1f,
                      float* __restrict__ theta_out) {
    const float PI = 3.14159265358979323846f;
    const float SC = 223.0f / 224.0f;
    int bid = blockIdx.x;

    if (bid < PACK_B) {                       // ---- image pack, 4 px/thread
        int i4 = bid*256 + threadIdx.x;
        if (i4 >= PACK_N4) return;
        int idx = i4 * 4;                     // pixel base; 50176 % 4 == 0 so
        int b  = idx / (IMGSZ*IMGSZ);         // all 4 px share one batch
        int px = idx - b*(IMGSZ*IMGSZ);
        const float* p = x + (size_t)b*3*IMGSZ*IMGSZ + px;
        f32x4 cr = *(const f32x4*)(p);
        f32x4 cg = *(const f32x4*)(p + IMGSZ*IMGSZ);
        f32x4 cb = *(const f32x4*)(p + 2*IMGSZ*IMGSZ);
        bf16x8 o0, o1;
        o0[0] = (__bf16)cr[0]; o0[1] = (__bf16)cg[0]; o0[2] = (__bf16)cb[0]; o0[3] = (__bf16)0.0f;
        o0[4] = (__bf16)cr[1]; o0[5] = (__bf16)cg[1]; o0[6] = (__bf16)cb[1]; o0[7] = (__bf16)0.0f;
        o1[0] = (__bf16)cr[2]; o1[1] = (__bf16)cg[2]; o1[2] = (__bf16)cb[2]; o1[3] = (__bf16)0.0f;
        o1[4] = (__bf16)cr[3]; o1[5] = (__bf16)cg[3]; o1[6] = (__bf16)cb[3]; o1[7] = (__bf16)0.0f;
        *(bf16x8*)(xp + (size_t)idx*4)     = o0;   // 16B, 32B-aligned
        *(bf16x8*)(xp + (size_t)idx*4 + 8) = o1;
        return;
    }

    int idx = (bid - PACK_B)*256 + threadIdx.x;
    if (idx < ED*ED*20) {
        // w2f: [(p*3+icb)*6+nt][lane][j], ic = icb*32+(lane>>4)*8+(j^sw)
        int j    = idx & 7;
        int lane = (idx >> 3) & 63;
        int grp  = idx >> 9;
        int nt   = grp % 6;
        int t    = grp / 6;
        int icb  = t % 3;
        int p    = t / 3;
        int sw   = (((p & 3) + icb) & 1) * 4;
        int oc = nt*16 + (lane & 15);
        int ic = icb*32 + (lane >> 4)*8 + (j ^ sw);
        w2f[idx] = (__bf16)w2[((size_t)(oc*ED + ic)*5 + (p >> 2))*4 + (p & 3)];
    } else if (idx < ED*ED*20 + 12*64*8) {
        // w1f: [grp=ks*6+ot][lane][j], A-frag value w1[oc][k]
        int i2   = idx - ED*ED*20;
        int j    = i2 & 7;
        int lane = (i2 >> 3) & 63;
        int grp  = i2 >> 9;
        int ks = grp / 6, ot = grp % 6;
        int oc = ot*16 + (lane & 15);
        int k  = ks*32 + (lane >> 4)*8 + j;
        w1f[i2] = (k < 60) ? (__bf16)w1[oc*60 + k] : (__bf16)0.0f;
    } else if (idx < ED*ED*20 + 12*64*8 + NBATCH*NR) {
        int i2 = idx - ED*ED*20 - 12*64*8;
        int b = i2 / NR, i = i2 % NR;
        float c0 = 0.2f + dist[b*4+0];
        float c1 = 0.2f + dist[b*4+1];
        float c2 = 0.2f + dist[b*4+2];
        float c3 = 0.2f + dist[b*4+3];
        float tmax = 0.5f * PI;
        float t  = tmax * ((float)i + 0.5f) / (float)NR;
        float t2 = t * t;
        float pt = t * (c0 + t2*(c1 + t2*(c2 + t2*c3)));
        float tm2 = tmax * tmax;
        float pm = tmax * (c0 + tm2*(c1 + tm2*(c2 + tm2*c3)));
        rtab[i2] = pt / pm * (0.5f * (float)IMGSZ);
    } else if (idx < ED*ED*20 + 12*64*8 + NBATCH*NR + NA) {
        int j = idx - ED*ED*20 - 12*64*8 - NBATCH*NR;
        float phi = 2.0f * PI * ((float)j + 0.5f) / (float)NA;
        costab[j] = cosf(phi) * SC;
        sintab[j] = sinf(phi) * SC;
    } else if (idx < PREP_N) {
        theta_out[idx - (ED*ED*20 + 12*64*8 + NBATCH*NR + NA)] = 0.5f * PI;
    }
}

// ---------------------------------------------------------------------------
// Mega kernel: polar bilinear sample (block-private region) -> conv1 (MFMA,
// D[oc][pixel]) -> t1f (conflict-free layout) -> conv2 (MFMA, wave =
// ka-quarter, register-accumulated over kr) -> reduce -> out.
// Block = (b, aq az-quarter, r2). Grid 2048, 256 thr = 4 waves.
//
// OCCUPANCY: counters show 57% issue-idle with all resident waves stalled
// simultaneously (correlated barrier/latency stalls) at 20 waves/CU.  This
// round evicts s_w1f from LDS: LDS 32576 -> 20288 B -> 8 blocks/CU = 32
// waves/CU, grid 2048 = exactly 8/CU, one uniform round.  w1 fragments are
// re-read from GLOBAL each kr (12 KB, L1/L2-resident, shared by all waves).
// Round-1 lesson: plain global reads get LICM-hoisted into ~96 VGPRs and
// spill under the 64-reg cap (FETCH 9->430 MB).  Fix: opaque per-iteration
// offset (asm volatile "+v") so the loads cannot be hoisted; live range is
// load -> 2 MFMAs -> dead, demand stays ~60 under __launch_bounds__(256,8).
// Loop body order: conv1 | bar | conv2 | sched_barrier | sample(kr+1) —
// so conv2's vmcnt waits never drain the sample gathers (in-order FIFO).
// ---------------------------------------------------------------------------
__global__ __launch_bounds__(256, 8)
void mega_kernel(const __bf16* __restrict__ xp,
                 const __bf16* __restrict__ w1f_g,
                 const __bf16* __restrict__ w2f,
                 const float* __restrict__ b1,
                 const float* __restrict__ b2,
                 const float* __restrict__ rtab,
                 const float* __restrict__ costab,
                 const float* __restrict__ sintab,
                 float* __restrict__ out) {
    __shared__ __attribute__((aligned(16))) char smem[20288];
    __bf16* s_samp = (__bf16*)smem;             // [15][266] elems 0..3989
    __bf16* t1f    = (__bf16*)(smem + 8000);    // [12 kk][4 quad][16 m][8]
    float*  red    = (float*)smem;              // [3][16][98] fp32 = 18816 B (aliases)

    int tid = threadIdx.x;
    int bid = blockIdx.x;                       // 2048
    int r2 = bid & 15;
    int aq = (bid >> 4) & 3;
    int b  = bid >> 6;
    int wave = tid >> 6, lane = tid & 63, l15 = lane & 15, quad = lane >> 4;

    // per-thread sampling constants: one azimuth column
    int az = aq*256 + tid;
    float sn = sintab[az];
    float cs = costab[az];
    const __bf16* xpb = xp + (size_t)b*IMGSZ*IMGSZ*4;
    const float* rb = rtab + b*NR + r2*25;

    f32x4 acc2[6];
    #pragma unroll
    for (int nt = 0; nt < 6; ++nt) acc2[nt] = (f32x4){0.f,0.f,0.f,0.f};

    // sample 5 radius rows (kr) x 3 ch into s_samp; stride-1 bf16 stores (free)
    auto sample = [&](int kr) {
        #pragma unroll
        for (int q = 0; q < 5; ++q) {
            float r  = rb[kr*5 + q];                       // wave-uniform
            float gx = fmaf(r, sn, 111.5f);
            float gy = fmaf(r, cs, 111.5f);
            float x0f = floorf(gx), y0f = floorf(gy);
            float wx1 = gx - x0f, wx0 = 1.0f - wx1;
            float wy1 = gy - y0f, wy0 = 1.0f - wy1;
            int ix = (int)x0f, iy = (int)y0f;
            ix = min(max(ix, 0), IMGSZ-2);                 // always in-bounds
            iy = min(max(iy, 0), IMGSZ-2);
            const __bf16* img = xpb + ((size_t)iy*IMGSZ + ix)*4;
            bf16x8u p0 = *(const bf16x8u*)img;             // row y: cols x0,x1
            bf16x8u p1 = *(const bf16x8u*)(img + IMGSZ*4); // row y+1
            float w00 = wy0*wx0, w01 = wy0*wx1, w10 = wy1*wx0, w11 = wy1*wx1;
            #pragma unroll
            for (int c = 0; c < 3; ++c) {
                float v = w00*(float)p0[c] + w01*(float)p0[4+c]
                        + w10*(float)p1[c] + w11*(float)p1[4+c];
                s_samp[(c*5 + q)*SROW + tid] = (__bf16)v;
            }
        }
    };

    sample(0);

    for (int kr = 0; kr < 5; ++kr) {
        __syncthreads();   // A: samples(kr) visible; prev conv2 t1f reads done

        // ---- conv1: wave = pixel-tile, pixel = wave*16 + l15 in [0,64)
        int colb = (wave*16 + l15)*4;
        f32x4 acc1[6];
        #pragma unroll
        for (int ot = 0; ot < 6; ++ot) acc1[ot] = (f32x4){0.f,0.f,0.f,0.f};

        frag_u fa, fb;
        fa.p.lo = *(const bf16x4a*)&s_samp[(quad*2    )*SROW + colb];
        fa.p.hi = *(const bf16x4a*)&s_samp[(quad*2 + 1)*SROW + colb];
        fb.p.lo = *(const bf16x4a*)&s_samp[(8 + quad*2)*SROW + colb];
        if (quad == 3) fb.p.hi = (bf16x4a){};
        else           fb.p.hi = *(const bf16x4a*)&s_samp[(9 + quad*2)*SROW + colb];

        // opaque offset: blocks LICM from hoisting the 12 w1 loads out of
        // the kr loop (round-1: hoist -> 96 VGPRs -> spill under 64-cap)
        int woff = 0;
        asm volatile("" : "+v"(woff));
        const __bf16* w1p = w1f_g + woff + (size_t)lane*8;

        #pragma unroll
        for (int ot = 0; ot < 6; ++ot) {
            bf16x8 wf0 = *(const bf16x8*)(w1p + (ot     )*512);
            bf16x8 wf1 = *(const bf16x8*)(w1p + (6 + ot )*512);
            acc1[ot] = __builtin_amdgcn_mfma_f32_16x16x32_bf16(wf0, fa.v, acc1[ot], 0, 0, 0);
            acc1[ot] = __builtin_amdgcn_mfma_f32_16x16x32_bf16(wf1, fb.v, acc1[ot], 0, 0, 0);
        }

        // epilogue: col=l15 (pixel), row=quad*4+r (oc=ic); scatter to t1f
        int pixel = wave*16 + l15;
        int a2l = pixel >> 2, ka = pixel & 3;
        #pragma unroll
        for (int ot = 0; ot < 6; ++ot) {
            f32x4 v = acc1[ot] + *(const f32x4*)(b1 + ot*16 + quad*4);
            bf16x4a wv;
            wv[0] = (__bf16)v[0]; wv[1] = (__bf16)v[1];
            wv[2] = (__bf16)v[2]; wv[3] = (__bf16)v[3];
            int icbase = ot*16 + quad*4;
            int kk = ka*3 + (icbase >> 5);
            int qT = (icbase >> 3) & 3;
            int jb = (icbase & 7) ^ ((kk & 1)*4);
            *(bf16x4a*)&t1f[((kk*4 + qT)*16 + a2l)*8 + jb] = wv;
        }
        __syncthreads();   // B: t1f ready; s_samp reads done

        // ---- conv2 FIRST: wave's ka = wave; 3 k-steps (vm loads self-owned)
        #pragma unroll
        for (int icb = 0; icb < 3; ++icb) {
            int kk = wave*3 + icb;
            int p  = kr*4 + wave;
            bf16x8 af = *(const bf16x8*)&t1f[(kk*64 + lane)*8];   // lane-contig
            const __bf16* wp = w2f + (size_t)((p*3 + icb)*6)*512 + lane*8;
            #pragma unroll
            for (int nt = 0; nt < 6; ++nt) {
                bf16x8 bf = *(const bf16x8*)(wp + nt*512);
                acc2[nt] = __builtin_amdgcn_mfma_f32_16x16x32_bf16(af, bf, acc2[nt], 0, 0, 0);
            }
        }

        // keep sample's gathers AFTER conv2's loads (vmcnt FIFO ordering)
        __builtin_amdgcn_sched_barrier(0);

        if (kr < 4) sample(kr + 1);   // gather latency hidden by other waves
    }

    // ---- ka-quarter reduction (red = 18816 B aliases s_samp+t1f = 20288 B)
    __syncthreads();
    if (wave) {
        float* rw = red + (wave - 1)*1568;     // 16*98
        #pragma unroll
        for (int nt = 0; nt < 6; ++nt)
            #pragma unroll
            for (int r = 0; r < 4; ++r)
                rw[(quad*4 + r)*98 + nt*16 + l15] = acc2[nt][r];
    }
    __syncthreads();
    if (wave == 0) {
        size_t ob = ((size_t)b*1024 + r2*64 + aq*16)*ED;
        #pragma unroll
        for (int nt = 0; nt < 6; ++nt) {
            int oc = nt*16 + l15;
            float bias = b2[oc];
            #pragma unroll
            for (int r = 0; r < 4; ++r) {
                int row = quad*4 + r;
                float v = acc2[nt][r] + bias
                        + red[row*98 + oc]
                        + red[1568 + row*98 + oc]
                        + red[3136 + row*98 + oc];
                out[ob + (size_t)row*ED + oc] = v;
            }
        }
    }
}

extern "C" void kernel_launch(void* const* d_in, const int* in_sizes, int n_in,
                              void* d_out, int out_size, void* d_ws, size_t ws_size,
                              hipStream_t stream) {
    const float* x    = (const float*)d_in[0];
    const float* dist = (const float*)d_in[1];
    const float* w1   = (const float*)d_in[2];
    const float* b1   = (const float*)d_in[3];
    const float* w2   = (const float*)d_in[4];
    const float* b2   = (const float*)d_in[5];
    float* out = (float*)d_out;

    float* rtab   = (float*)d_ws;                 // 12800 f32
    float* costab = rtab + NBATCH*NR;             // 1024 f32
    float* sintab = costab + NA;                  // 1024 f32
    __bf16* w2f   = (__bf16*)(sintab + NA);       // 184320 bf16
    __bf16* w1f   = w2f + ED*ED*20;               // 6144 bf16
    __bf16* xp    = w1f + 12*64*8;                // 32*224*224*4 bf16 (12.8MB)

    float* theta_out = out + (size_t)NBATCH*1024*ED;

    prep_pack_kernel<<<PACK_B + PREP_B, 256, 0, stream>>>(
        x, dist, w1, w2, xp, rtab, costab, sintab, w2f, w1f, theta_out);
    mega_kernel<<<NBATCH*16*4, 256, 0, stream>>>(
        xp, w1f, w2f, b1, b2, rtab, costab, sintab, out);
}

// Round 7
// 160.220 us; speedup vs baseline: 1.1969x; 1.1969x over previous
//
#include <hip/hip_runtime.h>
#include <hip/hip_bf16.h>
#include <math.h>

#define NBATCH 32
#define IMGSZ  224
#define NR     400
#define NA     1024
#define ED     96
#define SROW   266   // s_samp row stride in elems (256 cols + 10; odd dword)

typedef __attribute__((ext_vector_type(8))) __bf16 bf16x8;
typedef __attribute__((ext_vector_type(8), aligned(8))) __bf16 bf16x8u;
typedef __attribute__((ext_vector_type(4), aligned(8))) __bf16 bf16x4a;
typedef __attribute__((ext_vector_type(4))) __bf16 bf16x4;
typedef __attribute__((ext_vector_type(4))) float f32x4;

union frag_u { struct { bf16x4a lo, hi; } p; bf16x8 v; };

// ---------------------------------------------------------------------------
// ws layout (13.3 MB total):
//   rtab    f32 [32][400]
//   costab  f32 [1024]  (pre-scaled by 223/224)
//   sintab  f32 [1024]  (pre-scaled by 223/224)
//   w2f     bf16 [20*3*6][64][8]  fragment-major w2, j ^ ((ka+icb)&1)*4
//   w1f     bf16 [12][64][8]      fragment-major w1 (grp = ks*6+ot), k>=60 -> 0
//   xp      bf16 [32][224][224][4] channels-last packed image
// ---------------------------------------------------------------------------

#define PACK_N   (NBATCH*IMGSZ*IMGSZ)
#define PACK_N4  (PACK_N/4)               // 401408, exact
#define PACK_B   ((PACK_N4 + 255)/256)    // 1568, exact
#define PREP_N   (ED*ED*20 + 12*64*8 + NBATCH*NR + NA + NBATCH)
#define PREP_B   ((PREP_N + 255)/256)

// merged image pack (4 px/thread, float4 loads) + tables + weight reorder
__global__ __launch_bounds__(256)
void prep_pack_kernel(const float* __restrict__ x,
                      const float* __restrict__ dist,
                      const float* __restrict__ w1,
                      const float* __restrict__ w2,
                      __bf16* __restrict__ xp,
                      float* __restrict__ rtab,
                      float* __restrict__ costab,
                      float* __restrict__ sintab,
                      __bf16* __restrict__ w2f,
                      __bf16* __restrict__ w1f,
                      float* __restrict__ theta_out) {
    const float PI = 3.14159265358979323846f;
    const float SC = 223.0f / 224.0f;
    int bid = blockIdx.x;

    if (bid < PACK_B) {                       // ---- image pack, 4 px/thread
        int i4 = bid*256 + threadIdx.x;
        if (i4 >= PACK_N4) return;
        int idx = i4 * 4;                     // pixel base; 50176 % 4 == 0 so
        int b  = idx / (IMGSZ*IMGSZ);         // all 4 px share one batch
        int px = idx - b*(IMGSZ*IMGSZ);
        const float* p = x + (size_t)b*3*IMGSZ*IMGSZ + px;
        f32x4 cr = *(const f32x4*)(p);
        f32x4 cg = *(const f32x4*)(p + IMGSZ*IMGSZ);
        f32x4 cb = *(const f32x4*)(p + 2*IMGSZ*IMGSZ);
        bf16x8 o0, o1;
        o0[0] = (__bf16)cr[0]; o0[1] = (__bf16)cg[0]; o0[2] = (__bf16)cb[0]; o0[3] = (__bf16)0.0f;
        o0[4] = (__bf16)cr[1]; o0[5] = (__bf16)cg[1]; o0[6] = (__bf16)cb[1]; o0[7] = (__bf16)0.0f;
        o1[0] = (__bf16)cr[2]; o1[1] = (__bf16)cg[2]; o1[2] = (__bf16)cb[2]; o1[3] = (__bf16)0.0f;
        o1[4] = (__bf16)cr[3]; o1[5] = (__bf16)cg[3]; o1[6] = (__bf16)cb[3]; o1[7] = (__bf16)0.0f;
        *(bf16x8*)(xp + (size_t)idx*4)     = o0;   // 16B, 32B-aligned
        *(bf16x8*)(xp + (size_t)idx*4 + 8) = o1;
        return;
    }

    int idx = (bid - PACK_B)*256 + threadIdx.x;
    if (idx < ED*ED*20) {
        // w2f: [(p*3+icb)*6+nt][lane][j], ic = icb*32+(lane>>4)*8+(j^sw)
        int j    = idx & 7;
        int lane = (idx >> 3) & 63;
        int grp  = idx >> 9;
        int nt   = grp % 6;
        int t    = grp / 6;
        int icb  = t % 3;
        int p    = t / 3;
        int sw   = (((p & 3) + icb) & 1) * 4;
        int oc = nt*16 + (lane & 15);
        int ic = icb*32 + (lane >> 4)*8 + (j ^ sw);
        w2f[idx] = (__bf16)w2[((size_t)(oc*ED + ic)*5 + (p >> 2))*4 + (p & 3)];
    } else if (idx < ED*ED*20 + 12*64*8) {
        // w1f: [grp=ks*6+ot][lane][j], A-frag value w1[oc][k]
        int i2   = idx - ED*ED*20;
        int j    = i2 & 7;
        int lane = (i2 >> 3) & 63;
        int grp  = i2 >> 9;
        int ks = grp / 6, ot = grp % 6;
        int oc = ot*16 + (lane & 15);
        int k  = ks*32 + (lane >> 4)*8 + j;
        w1f[i2] = (k < 60) ? (__bf16)w1[oc*60 + k] : (__bf16)0.0f;
    } else if (idx < ED*ED*20 + 12*64*8 + NBATCH*NR) {
        int i2 = idx - ED*ED*20 - 12*64*8;
        int b = i2 / NR, i = i2 % NR;
        float c0 = 0.2f + dist[b*4+0];
        float c1 = 0.2f + dist[b*4+1];
        float c2 = 0.2f + dist[b*4+2];
        float c3 = 0.2f + dist[b*4+3];
        float tmax = 0.5f * PI;
        float t  = tmax * ((float)i + 0.5f) / (float)NR;
        float t2 = t * t;
        float pt = t * (c0 + t2*(c1 + t2*(c2 + t2*c3)));
        float tm2 = tmax * tmax;
        float pm = tmax * (c0 + tm2*(c1 + tm2*(c2 + tm2*c3)));
        rtab[i2] = pt / pm * (0.5f * (float)IMGSZ);
    } else if (idx < ED*ED*20 + 12*64*8 + NBATCH*NR + NA) {
        int j = idx - ED*ED*20 - 12*64*8 - NBATCH*NR;
        float phi = 2.0f * PI * ((float)j + 0.5f) / (float)NA;
        costab[j] = cosf(phi) * SC;
        sintab[j] = sinf(phi) * SC;
    } else if (idx < PREP_N) {
        theta_out[idx - (ED*ED*20 + 12*64*8 + NBATCH*NR + NA)] = 0.5f * PI;
    }
}

// ---------------------------------------------------------------------------
// Mega kernel: polar bilinear sample (block-private region) -> conv1 (MFMA,
// D[oc][pixel], per-ot fused epilogue) -> t1f -> conv2 (MFMA, wave =
// ka-quarter, register-accumulated over kr) -> reduce -> out.
// Block = (b, aq az-quarter, r2). Grid 2048, 256 thr = 4 waves.
//
// REGISTER OCCUPANCY MODEL (round-6 lesson): per-EU reg file = 512; the
// launch-bounds wave target sets cap = 512/waves_per_EU on TOTAL arch+accum
// regs (rocprof VGPR_Count is arch-only!).  This kernel's demand ~108 regs
// -> bucket 128 -> only 4 waves/EU (16/CU); LDS (5 blocks) never binds.
// (256,8): cap 64 -> ~50 regs spilled -> 160 MB scratch (R1, R6: proven
// twice).  This round targets the NEXT bucket: (256,5) -> cap 102 -> 20
// waves/CU, overshoot only ~6 regs; plus per-ot conv1 epilogue fusion so
// acc1 shrinks from 6 live tiles (24 regs) to 1-2.  Spill tripwire:
// WRITE_SIZE >> 12.3 MB.
// Loop body order: conv1 | bar | conv2 | sched_barrier | sample(kr+1) —
// so conv2's vmcnt waits never drain the sample gathers (in-order FIFO).
// ---------------------------------------------------------------------------
__global__ __launch_bounds__(256, 5)
void mega_kernel(const __bf16* __restrict__ xp,
                 const __bf16* __restrict__ w1f_g,
                 const __bf16* __restrict__ w2f,
                 const float* __restrict__ b1,
                 const float* __restrict__ b2,
                 const float* __restrict__ rtab,
                 const float* __restrict__ costab,
                 const float* __restrict__ sintab,
                 float* __restrict__ out) {
    __shared__ __attribute__((aligned(16))) char smem[32576];
    __bf16* s_samp = (__bf16*)smem;             // [15][266] elems 0..3989
    __bf16* t1f    = (__bf16*)(smem + 8000);    // [12 kk][4 quad][16 m][8]
    __bf16* s_w1f  = (__bf16*)(smem + 20288);   // [12 grp][64 lane][8]
    float*  red    = (float*)smem;              // [3][16][98] fp32 (aliases)

    int tid = threadIdx.x;
    int bid = blockIdx.x;                       // 2048
    int r2 = bid & 15;
    int aq = (bid >> 4) & 3;
    int b  = bid >> 6;
    int wave = tid >> 6, lane = tid & 63, l15 = lane & 15, quad = lane >> 4;

    // stage w1 fragments into LDS (12288 B, coalesced)
    #pragma unroll
    for (int i = 0; i < 3; ++i)
        *(bf16x8*)(s_w1f + i*2048 + tid*8) = *(const bf16x8*)(w1f_g + i*2048 + tid*8);

    // per-thread sampling constants: one azimuth column
    int az = aq*256 + tid;
    float sn = sintab[az];
    float cs = costab[az];
    const __bf16* xpb = xp + (size_t)b*IMGSZ*IMGSZ*4;
    const float* rb = rtab + b*NR + r2*25;

    f32x4 acc2[6];
    #pragma unroll
    for (int nt = 0; nt < 6; ++nt) acc2[nt] = (f32x4){0.f,0.f,0.f,0.f};

    // sample 5 radius rows (kr) x 3 ch into s_samp; stride-1 bf16 stores (free)
    auto sample = [&](int kr) {
        #pragma unroll
        for (int q = 0; q < 5; ++q) {
            float r  = rb[kr*5 + q];                       // wave-uniform
            float gx = fmaf(r, sn, 111.5f);
            float gy = fmaf(r, cs, 111.5f);
            float x0f = floorf(gx), y0f = floorf(gy);
            float wx1 = gx - x0f, wx0 = 1.0f - wx1;
            float wy1 = gy - y0f, wy0 = 1.0f - wy1;
            int ix = (int)x0f, iy = (int)y0f;
            ix = min(max(ix, 0), IMGSZ-2);                 // always in-bounds
            iy = min(max(iy, 0), IMGSZ-2);
            const __bf16* img = xpb + ((size_t)iy*IMGSZ + ix)*4;
            bf16x8u p0 = *(const bf16x8u*)img;             // row y: cols x0,x1
            bf16x8u p1 = *(const bf16x8u*)(img + IMGSZ*4); // row y+1
            float w00 = wy0*wx0, w01 = wy0*wx1, w10 = wy1*wx0, w11 = wy1*wx1;
            #pragma unroll
            for (int c = 0; c < 3; ++c) {
                float v = w00*(float)p0[c] + w01*(float)p0[4+c]
                        + w10*(float)p1[c] + w11*(float)p1[4+c];
                s_samp[(c*5 + q)*SROW + tid] = (__bf16)v;
            }
        }
    };

    sample(0);

    for (int kr = 0; kr < 5; ++kr) {
        __syncthreads();   // A: samples(kr) visible; prev conv2 t1f reads done

        // ---- conv1: wave = pixel-tile, pixel = wave*16 + l15 in [0,64)
        int colb = (wave*16 + l15)*4;

        frag_u fa, fb;
        fa.p.lo = *(const bf16x4a*)&s_samp[(quad*2    )*SROW + colb];
        fa.p.hi = *(const bf16x4a*)&s_samp[(quad*2 + 1)*SROW + colb];
        fb.p.lo = *(const bf16x4a*)&s_samp[(8 + quad*2)*SROW + colb];
        if (quad == 3) fb.p.hi = (bf16x4a){};
        else           fb.p.hi = *(const bf16x4a*)&s_samp[(9 + quad*2)*SROW + colb];

        // per-ot fused epilogue: 2 MFMAs -> bias -> cvt -> t1f store, then
        // next ot.  Keeps 1-2 acc tiles live instead of 6 (saves ~16-20
        // regs); allocator may still pipeline across ot when slack exists.
        int pixel = wave*16 + l15;
        int a2l = pixel >> 2, ka = pixel & 3;
        #pragma unroll
        for (int ot = 0; ot < 6; ++ot) {
            bf16x8 wf0 = *(const bf16x8*)(s_w1f + (ot     )*512 + lane*8);
            bf16x8 wf1 = *(const bf16x8*)(s_w1f + (6 + ot )*512 + lane*8);
            f32x4 a = (f32x4){0.f,0.f,0.f,0.f};
            a = __builtin_amdgcn_mfma_f32_16x16x32_bf16(wf0, fa.v, a, 0, 0, 0);
            a = __builtin_amdgcn_mfma_f32_16x16x32_bf16(wf1, fb.v, a, 0, 0, 0);
            f32x4 v = a + *(const f32x4*)(b1 + ot*16 + quad*4);
            bf16x4a wv;
            wv[0] = (__bf16)v[0]; wv[1] = (__bf16)v[1];
            wv[2] = (__bf16)v[2]; wv[3] = (__bf16)v[3];
            int icbase = ot*16 + quad*4;
            int kk = ka*3 + (icbase >> 5);
            int qT = (icbase >> 3) & 3;
            int jb = (icbase & 7) ^ ((kk & 1)*4);
            *(bf16x4a*)&t1f[((kk*4 + qT)*16 + a2l)*8 + jb] = wv;
        }
        __syncthreads();   // B: t1f ready; s_samp reads done

        // ---- conv2 FIRST: wave's ka = wave; 3 k-steps (vm loads self-owned)
        #pragma unroll
        for (int icb = 0; icb < 3; ++icb) {
            int kk = wave*3 + icb;
            int p  = kr*4 + wave;
            bf16x8 af = *(const bf16x8*)&t1f[(kk*64 + lane)*8];   // lane-contig
            const __bf16* wp = w2f + (size_t)((p*3 + icb)*6)*512 + lane*8;
            #pragma unroll
            for (int nt = 0; nt < 6; ++nt) {
                bf16x8 bf = *(const bf16x8*)(wp + nt*512);
                acc2[nt] = __builtin_amdgcn_mfma_f32_16x16x32_bf16(af, bf, acc2[nt], 0, 0, 0);
            }
        }

        // keep sample's gathers AFTER conv2's loads (vmcnt FIFO ordering)
        __builtin_amdgcn_sched_barrier(0);

        if (kr < 4) sample(kr + 1);   // gather latency hidden by other waves
    }

    // ---- ka-quarter reduction (red aliases s_samp+t1f; w1f region untouched)
    __syncthreads();
    if (wave) {
        float* rw = red + (wave - 1)*1568;     // 16*98
        #pragma unroll
        for (int nt = 0; nt < 6; ++nt)
            #pragma unroll
            for (int r = 0; r < 4; ++r)
                rw[(quad*4 + r)*98 + nt*16 + l15] = acc2[nt][r];
    }
    __syncthreads();
    if (wave == 0) {
        size_t ob = ((size_t)b*1024 + r2*64 + aq*16)*ED;
        #pragma unroll
        for (int nt = 0; nt < 6; ++nt) {
            int oc = nt*16 + l15;
            float bias = b2[oc];
            #pragma unroll
            for (int r = 0; r < 4; ++r) {
                int row = quad*4 + r;
                float v = acc2[nt][r] + bias
                        + red[row*98 + oc]
                        + red[1568 + row*98 + oc]
                        + red[3136 + row*98 + oc];
                out[ob + (size_t)row*ED + oc] = v;
            }
        }
    }
}

extern "C" void kernel_launch(void* const* d_in, const int* in_sizes, int n_in,
                              void* d_out, int out_size, void* d_ws, size_t ws_size,
                              hipStream_t stream) {
    const float* x    = (const float*)d_in[0];
    const float* dist = (const float*)d_in[1];
    const float* w1   = (const float*)d_in[2];
    const float* b1   = (const float*)d_in[3];
    const float* w2   = (const float*)d_in[4];
    const float* b2   = (const float*)d_in[5];
    float* out = (float*)d_out;

    float* rtab   = (float*)d_ws;                 // 12800 f32
    float* costab = rtab + NBATCH*NR;             // 1024 f32
    float* sintab = costab + NA;                  // 1024 f32
    __bf16* w2f   = (__bf16*)(sintab + NA);       // 184320 bf16
    __bf16* w1f   = w2f + ED*ED*20;               // 6144 bf16
    __bf16* xp    = w1f + 12*64*8;                // 32*224*224*4 bf16 (12.8MB)

    float* theta_out = out + (size_t)NBATCH*1024*ED;

    prep_pack_kernel<<<PACK_B + PREP_B, 256, 0, stream>>>(
        x, dist, w1, w2, xp, rtab, costab, sintab, w2f, w1f, theta_out);
    mega_kernel<<<NBATCH*16*4, 256, 0, stream>>>(
        xp, w1f, w2f, b1, b2, rtab, costab, sintab, out);
}

// Round 8
// 157.310 us; speedup vs baseline: 1.2191x; 1.0185x over previous
//
#include <hip/hip_runtime.h>
#include <hip/hip_bf16.h>
#include <math.h>

#define NBATCH 32
#define IMGSZ  224
#define NR     400
#define NA     1024
#define ED     96
#define SROW   266   // s_samp row stride in elems (256 cols + 10; odd dword)

typedef __attribute__((ext_vector_type(8))) __bf16 bf16x8;
typedef __attribute__((ext_vector_type(8), aligned(8))) __bf16 bf16x8u;
typedef __attribute__((ext_vector_type(4), aligned(8))) __bf16 bf16x4a;
typedef __attribute__((ext_vector_type(4))) __bf16 bf16x4;
typedef __attribute__((ext_vector_type(4))) float f32x4;

union frag_u { struct { bf16x4a lo, hi; } p; bf16x8 v; };

// ---------------------------------------------------------------------------
// ws layout (13.3 MB total):
//   rtab    f32 [32][400]
//   costab  f32 [1024]  (pre-scaled by 223/224)
//   sintab  f32 [1024]  (pre-scaled by 223/224)
//   w2f     bf16 [20*3*6][64][8]  fragment-major w2, j ^ ((ka+icb)&1)*4
//   w1f     bf16 [12][64][8]      fragment-major w1 (grp = ks*6+ot), k>=60 -> 0
//   xp      bf16 [32][224][224][4] channels-last packed image
// ---------------------------------------------------------------------------

#define PACK_N   (NBATCH*IMGSZ*IMGSZ)
#define PACK_N4  (PACK_N/4)               // 401408, exact
#define PACK_B   ((PACK_N4 + 255)/256)    // 1568, exact
#define PREP_N   (ED*ED*20 + 12*64*8 + NBATCH*NR + NA + NBATCH)
#define PREP_B   ((PREP_N + 255)/256)

// merged image pack (4 px/thread, float4 loads) + tables + weight reorder
__global__ __launch_bounds__(256)
void prep_pack_kernel(const float* __restrict__ x,
                      const float* __restrict__ dist,
                      const float* __restrict__ w1,
                      const float* __restrict__ w2,
                      __bf16* __restrict__ xp,
                      float* __restrict__ rtab,
                      float* __restrict__ costab,
                      float* __restrict__ sintab,
                      __bf16* __restrict__ w2f,
                      __bf16* __restrict__ w1f,
                      float* __restrict__ theta_out) {
    const float PI = 3.14159265358979323846f;
    const float SC = 223.0f / 224.0f;
    int bid = blockIdx.x;

    if (bid < PACK_B) {                       // ---- image pack, 4 px/thread
        int i4 = bid*256 + threadIdx.x;
        if (i4 >= PACK_N4) return;
        int idx = i4 * 4;                     // pixel base; 50176 % 4 == 0 so
        int b  = idx / (IMGSZ*IMGSZ);         // all 4 px share one batch
        int px = idx - b*(IMGSZ*IMGSZ);
        const float* p = x + (size_t)b*3*IMGSZ*IMGSZ + px;
        f32x4 cr = *(const f32x4*)(p);
        f32x4 cg = *(const f32x4*)(p + IMGSZ*IMGSZ);
        f32x4 cb = *(const f32x4*)(p + 2*IMGSZ*IMGSZ);
        bf16x8 o0, o1;
        o0[0] = (__bf16)cr[0]; o0[1] = (__bf16)cg[0]; o0[2] = (__bf16)cb[0]; o0[3] = (__bf16)0.0f;
        o0[4] = (__bf16)cr[1]; o0[5] = (__bf16)cg[1]; o0[6] = (__bf16)cb[1]; o0[7] = (__bf16)0.0f;
        o1[0] = (__bf16)cr[2]; o1[1] = (__bf16)cg[2]; o1[2] = (__bf16)cb[2]; o1[3] = (__bf16)0.0f;
        o1[4] = (__bf16)cr[3]; o1[5] = (__bf16)cg[3]; o1[6] = (__bf16)cb[3]; o1[7] = (__bf16)0.0f;
        *(bf16x8*)(xp + (size_t)idx*4)     = o0;   // 16B, 32B-aligned
        *(bf16x8*)(xp + (size_t)idx*4 + 8) = o1;
        return;
    }

    int idx = (bid - PACK_B)*256 + threadIdx.x;
    if (idx < ED*ED*20) {
        // w2f: [(p*3+icb)*6+nt][lane][j], ic = icb*32+(lane>>4)*8+(j^sw)
        int j    = idx & 7;
        int lane = (idx >> 3) & 63;
        int grp  = idx >> 9;
        int nt   = grp % 6;
        int t    = grp / 6;
        int icb  = t % 3;
        int p    = t / 3;
        int sw   = (((p & 3) + icb) & 1) * 4;
        int oc = nt*16 + (lane & 15);
        int ic = icb*32 + (lane >> 4)*8 + (j ^ sw);
        w2f[idx] = (__bf16)w2[((size_t)(oc*ED + ic)*5 + (p >> 2))*4 + (p & 3)];
    } else if (idx < ED*ED*20 + 12*64*8) {
        // w1f: [grp=ks*6+ot][lane][j], A-frag value w1[oc][k]
        int i2   = idx - ED*ED*20;
        int j    = i2 & 7;
        int lane = (i2 >> 3) & 63;
        int grp  = i2 >> 9;
        int ks = grp / 6, ot = grp % 6;
        int oc = ot*16 + (lane & 15);
        int k  = ks*32 + (lane >> 4)*8 + j;
        w1f[i2] = (k < 60) ? (__bf16)w1[oc*60 + k] : (__bf16)0.0f;
    } else if (idx < ED*ED*20 + 12*64*8 + NBATCH*NR) {
        int i2 = idx - ED*ED*20 - 12*64*8;
        int b = i2 / NR, i = i2 % NR;
        float c0 = 0.2f + dist[b*4+0];
        float c1 = 0.2f + dist[b*4+1];
        float c2 = 0.2f + dist[b*4+2];
        float c3 = 0.2f + dist[b*4+3];
        float tmax = 0.5f * PI;
        float t  = tmax * ((float)i + 0.5f) / (float)NR;
        float t2 = t * t;
        float pt = t * (c0 + t2*(c1 + t2*(c2 + t2*c3)));
        float tm2 = tmax * tmax;
        float pm = tmax * (c0 + tm2*(c1 + tm2*(c2 + tm2*c3)));
        rtab[i2] = pt / pm * (0.5f * (float)IMGSZ);
    } else if (idx < ED*ED*20 + 12*64*8 + NBATCH*NR + NA) {
        int j = idx - ED*ED*20 - 12*64*8 - NBATCH*NR;
        float phi = 2.0f * PI * ((float)j + 0.5f) / (float)NA;
        costab[j] = cosf(phi) * SC;
        sintab[j] = sinf(phi) * SC;
    } else if (idx < PREP_N) {
        theta_out[idx - (ED*ED*20 + 12*64*8 + NBATCH*NR + NA)] = 0.5f * PI;
    }
}

// ---------------------------------------------------------------------------
// Mega kernel: EXACT round-0 structure (acc1[6] restored — its 12 independent
// MFMA chains are load-bearing ILP; round-7's per-ot fusion serialized them,
// -28%).  ONE variable changed vs round 0: __launch_bounds__(256,5).
//
// Register-occupancy model: per-EU reg file 512; (256,4) caps total regs at
// 128 -> if demand ~108, only 4 waves/EU (16/CU) resident even though LDS
// (32576 B) allows 5 blocks (20 waves).  (256,5) caps at 102; round-7 proved
// the compiler can fit this kernel ~<=100 total WITHOUT spill (FETCH/WRITE
// stayed 9/12.3 MB).  If it fits: +25% resident waves on a kernel that is
// 57% issue-idle.  Spill tripwire: WRITE_SIZE >> 12.3 MB (then (256,4)
// revert is final).  (256,8)=cap64 proven catastrophic twice (R1,R6).
// Loop body order: conv1 | bar | conv2 | sched_barrier | sample(kr+1) —
// so conv2's vmcnt waits never drain the sample gathers (in-order FIFO).
// ---------------------------------------------------------------------------
__global__ __launch_bounds__(256, 5)
void mega_kernel(const __bf16* __restrict__ xp,
                 const __bf16* __restrict__ w1f_g,
                 const __bf16* __restrict__ w2f,
                 const float* __restrict__ b1,
                 const float* __restrict__ b2,
                 const float* __restrict__ rtab,
                 const float* __restrict__ costab,
                 const float* __restrict__ sintab,
                 float* __restrict__ out) {
    __shared__ __attribute__((aligned(16))) char smem[32576];
    __bf16* s_samp = (__bf16*)smem;             // [15][266] elems 0..3989
    __bf16* t1f    = (__bf16*)(smem + 8000);    // [12 kk][4 quad][16 m][8]
    __bf16* s_w1f  = (__bf16*)(smem + 20288);   // [12 grp][64 lane][8]
    float*  red    = (float*)smem;              // [3][16][98] fp32 (aliases)

    int tid = threadIdx.x;
    int bid = blockIdx.x;                       // 2048
    int r2 = bid & 15;
    int aq = (bid >> 4) & 3;
    int b  = bid >> 6;
    int wave = tid >> 6, lane = tid & 63, l15 = lane & 15, quad = lane >> 4;

    // stage w1 fragments into LDS (12288 B, coalesced)
    #pragma unroll
    for (int i = 0; i < 3; ++i)
        *(bf16x8*)(s_w1f + i*2048 + tid*8) = *(const bf16x8*)(w1f_g + i*2048 + tid*8);

    // per-thread sampling constants: one azimuth column
    int az = aq*256 + tid;
    float sn = sintab[az];
    float cs = costab[az];
    const __bf16* xpb = xp + (size_t)b*IMGSZ*IMGSZ*4;
    const float* rb = rtab + b*NR + r2*25;

    f32x4 acc2[6];
    #pragma unroll
    for (int nt = 0; nt < 6; ++nt) acc2[nt] = (f32x4){0.f,0.f,0.f,0.f};

    // sample 5 radius rows (kr) x 3 ch into s_samp; stride-1 bf16 stores (free)
    auto sample = [&](int kr) {
        #pragma unroll
        for (int q = 0; q < 5; ++q) {
            float r  = rb[kr*5 + q];                       // wave-uniform
            float gx = fmaf(r, sn, 111.5f);
            float gy = fmaf(r, cs, 111.5f);
            float x0f = floorf(gx), y0f = floorf(gy);
            float wx1 = gx - x0f, wx0 = 1.0f - wx1;
            float wy1 = gy - y0f, wy0 = 1.0f - wy1;
            int ix = (int)x0f, iy = (int)y0f;
            ix = min(max(ix, 0), IMGSZ-2);                 // always in-bounds
            iy = min(max(iy, 0), IMGSZ-2);
            const __bf16* img = xpb + ((size_t)iy*IMGSZ + ix)*4;
            bf16x8u p0 = *(const bf16x8u*)img;             // row y: cols x0,x1
            bf16x8u p1 = *(const bf16x8u*)(img + IMGSZ*4); // row y+1
            float w00 = wy0*wx0, w01 = wy0*wx1, w10 = wy1*wx0, w11 = wy1*wx1;
            #pragma unroll
            for (int c = 0; c < 3; ++c) {
                float v = w00*(float)p0[c] + w01*(float)p0[4+c]
                        + w10*(float)p1[c] + w11*(float)p1[4+c];
                s_samp[(c*5 + q)*SROW + tid] = (__bf16)v;
            }
        }
    };

    sample(0);

    for (int kr = 0; kr < 5; ++kr) {
        __syncthreads();   // A: samples(kr) visible; prev conv2 t1f reads done

        // ---- conv1: wave = pixel-tile, pixel = wave*16 + l15 in [0,64)
        int colb = (wave*16 + l15)*4;
        f32x4 acc1[6];
        #pragma unroll
        for (int ot = 0; ot < 6; ++ot) acc1[ot] = (f32x4){0.f,0.f,0.f,0.f};

        frag_u fa, fb;
        fa.p.lo = *(const bf16x4a*)&s_samp[(quad*2    )*SROW + colb];
        fa.p.hi = *(const bf16x4a*)&s_samp[(quad*2 + 1)*SROW + colb];
        fb.p.lo = *(const bf16x4a*)&s_samp[(8 + quad*2)*SROW + colb];
        if (quad == 3) fb.p.hi = (bf16x4a){};
        else           fb.p.hi = *(const bf16x4a*)&s_samp[(9 + quad*2)*SROW + colb];

        #pragma unroll
        for (int ot = 0; ot < 6; ++ot) {
            bf16x8 wf0 = *(const bf16x8*)(s_w1f + (ot     )*512 + lane*8);
            bf16x8 wf1 = *(const bf16x8*)(s_w1f + (6 + ot )*512 + lane*8);
            acc1[ot] = __builtin_amdgcn_mfma_f32_16x16x32_bf16(wf0, fa.v, acc1[ot], 0, 0, 0);
            acc1[ot] = __builtin_amdgcn_mfma_f32_16x16x32_bf16(wf1, fb.v, acc1[ot], 0, 0, 0);
        }

        // epilogue: col=l15 (pixel), row=quad*4+r (oc=ic); scatter to t1f
        int pixel = wave*16 + l15;
        int a2l = pixel >> 2, ka = pixel & 3;
        #pragma unroll
        for (int ot = 0; ot < 6; ++ot) {
            f32x4 v = acc1[ot] + *(const f32x4*)(b1 + ot*16 + quad*4);
            bf16x4a wv;
            wv[0] = (__bf16)v[0]; wv[1] = (__bf16)v[1];
            wv[2] = (__bf16)v[2]; wv[3] = (__bf16)v[3];
            int icbase = ot*16 + quad*4;
            int kk = ka*3 + (icbase >> 5);
            int qT = (icbase >> 3) & 3;
            int jb = (icbase & 7) ^ ((kk & 1)*4);
            *(bf16x4a*)&t1f[((kk*4 + qT)*16 + a2l)*8 + jb] = wv;
        }
        __syncthreads();   // B: t1f ready; s_samp reads done

        // ---- conv2 FIRST: wave's ka = wave; 3 k-steps (vm loads self-owned)
        #pragma unroll
        for (int icb = 0; icb < 3; ++icb) {
            int kk = wave*3 + icb;
            int p  = kr*4 + wave;
            bf16x8 af = *(const bf16x8*)&t1f[(kk*64 + lane)*8];   // lane-contig
            const __bf16* wp = w2f + (size_t)((p*3 + icb)*6)*512 + lane*8;
            #pragma unroll
            for (int nt = 0; nt < 6; ++nt) {
                bf16x8 bf = *(const bf16x8*)(wp + nt*512);
                acc2[nt] = __builtin_amdgcn_mfma_f32_16x16x32_bf16(af, bf, acc2[nt], 0, 0, 0);
            }
        }

        // keep sample's gathers AFTER conv2's loads (vmcnt FIFO ordering)
        __builtin_amdgcn_sched_barrier(0);

        if (kr < 4) sample(kr + 1);   // gather latency hidden by other waves
    }

    // ---- ka-quarter reduction (red aliases s_samp+t1f; w1f region untouched)
    __syncthreads();
    if (wave) {
        float* rw = red + (wave - 1)*1568;     // 16*98
        #pragma unroll
        for (int nt = 0; nt < 6; ++nt)
            #pragma unroll
            for (int r = 0; r < 4; ++r)
                rw[(quad*4 + r)*98 + nt*16 + l15] = acc2[nt][r];
    }
    __syncthreads();
    if (wave == 0) {
        size_t ob = ((size_t)b*1024 + r2*64 + aq*16)*ED;
        #pragma unroll
        for (int nt = 0; nt < 6; ++nt) {
            int oc = nt*16 + l15;
            float bias = b2[oc];
            #pragma unroll
            for (int r = 0; r < 4; ++r) {
                int row = quad*4 + r;
                float v = acc2[nt][r] + bias
                        + red[row*98 + oc]
                        + red[1568 + row*98 + oc]
                        + red[3136 + row*98 + oc];
                out[ob + (size_t)row*ED + oc] = v;
            }
        }
    }
}

extern "C" void kernel_launch(void* const* d_in, const int* in_sizes, int n_in,
                              void* d_out, int out_size, void* d_ws, size_t ws_size,
                              hipStream_t stream) {
    const float* x    = (const float*)d_in[0];
    const float* dist = (const float*)d_in[1];
    const float* w1   = (const float*)d_in[2];
    const float* b1   = (const float*)d_in[3];
    const float* w2   = (const float*)d_in[4];
    const float* b2   = (const float*)d_in[5];
    float* out = (float*)d_out;

    float* rtab   = (float*)d_ws;                 // 12800 f32
    float* costab = rtab + NBATCH*NR;             // 1024 f32
    float* sintab = costab + NA;                  // 1024 f32
    __bf16* w2f   = (__bf16*)(sintab + NA);       // 184320 bf16
    __bf16* w1f   = w2f + ED*ED*20;               // 6144 bf16
    __bf16* xp    = w1f + 12*64*8;                // 32*224*224*4 bf16 (12.8MB)

    float* theta_out = out + (size_t)NBATCH*1024*ED;

    prep_pack_kernel<<<PACK_B + PREP_B, 256, 0, stream>>>(
        x, dist, w1, w2, xp, rtab, costab, sintab, w2f, w1f, theta_out);
    mega_kernel<<<NBATCH*16*4, 256, 0, stream>>>(
        xp, w1f, w2f, b1, b2, rtab, costab, sintab, out);
}

// Round 9
// 139.776 us; speedup vs baseline: 1.3720x; 1.1254x over previous
//
#include <hip/hip_runtime.h>
#include <hip/hip_bf16.h>
#include <math.h>

#define NBATCH 32
#define IMGSZ  224
#define NR     400
#define NA     1024
#define ED     96
#define SROW   256   // s_samp row stride: 4 wave-private slabs of 64 cols

typedef __attribute__((ext_vector_type(8))) __bf16 bf16x8;
typedef __attribute__((ext_vector_type(8), aligned(8))) __bf16 bf16x8u;
typedef __attribute__((ext_vector_type(4), aligned(8))) __bf16 bf16x4a;
typedef __attribute__((ext_vector_type(4))) __bf16 bf16x4;
typedef __attribute__((ext_vector_type(4))) float f32x4;

union frag_u { struct { bf16x4a lo, hi; } p; bf16x8 v; };

// ---------------------------------------------------------------------------
// ws layout (13.3 MB total):
//   rtab    f32 [32][400]
//   costab  f32 [1024]  (pre-scaled by 223/224)
//   sintab  f32 [1024]  (pre-scaled by 223/224)
//   w2f     bf16 [20*3*6][64][8]  fragment-major w2, j ^ ((ka+icb)&1)*4
//   w1f     bf16 [12][64][8]      fragment-major w1 (grp = ks*6+ot), k>=60 -> 0
//   xp      bf16 [32][224][224][4] channels-last packed image
// ---------------------------------------------------------------------------

#define PACK_N   (NBATCH*IMGSZ*IMGSZ)
#define PACK_N4  (PACK_N/4)               // 401408, exact
#define PACK_B   ((PACK_N4 + 255)/256)    // 1568, exact
#define PREP_N   (ED*ED*20 + 12*64*8 + NBATCH*NR + NA + NBATCH)
#define PREP_B   ((PREP_N + 255)/256)

// merged image pack (4 px/thread, float4 loads) + tables + weight reorder
__global__ __launch_bounds__(256)
void prep_pack_kernel(const float* __restrict__ x,
                      const float* __restrict__ dist,
                      const float* __restrict__ w1,
                      const float* __restrict__ w2,
                      __bf16* __restrict__ xp,
                      float* __restrict__ rtab,
                      float* __restrict__ costab,
                      float* __restrict__ sintab,
                      __bf16* __restrict__ w2f,
                      __bf16* __restrict__ w1f,
                      float* __restrict__ theta_out) {
    const float PI = 3.14159265358979323846f;
    const float SC = 223.0f / 224.0f;
    int bid = blockIdx.x;

    if (bid < PACK_B) {                       // ---- image pack, 4 px/thread
        int i4 = bid*256 + threadIdx.x;
        if (i4 >= PACK_N4) return;
        int idx = i4 * 4;                     // pixel base; 50176 % 4 == 0 so
        int b  = idx / (IMGSZ*IMGSZ);         // all 4 px share one batch
        int px = idx - b*(IMGSZ*IMGSZ);
        const float* p = x + (size_t)b*3*IMGSZ*IMGSZ + px;
        f32x4 cr = *(const f32x4*)(p);
        f32x4 cg = *(const f32x4*)(p + IMGSZ*IMGSZ);
        f32x4 cb = *(const f32x4*)(p + 2*IMGSZ*IMGSZ);
        bf16x8 o0, o1;
        o0[0] = (__bf16)cr[0]; o0[1] = (__bf16)cg[0]; o0[2] = (__bf16)cb[0]; o0[3] = (__bf16)0.0f;
        o0[4] = (__bf16)cr[1]; o0[5] = (__bf16)cg[1]; o0[6] = (__bf16)cb[1]; o0[7] = (__bf16)0.0f;
        o1[0] = (__bf16)cr[2]; o1[1] = (__bf16)cg[2]; o1[2] = (__bf16)cb[2]; o1[3] = (__bf16)0.0f;
        o1[4] = (__bf16)cr[3]; o1[5] = (__bf16)cg[3]; o1[6] = (__bf16)cb[3]; o1[7] = (__bf16)0.0f;
        *(bf16x8*)(xp + (size_t)idx*4)     = o0;   // 16B, 32B-aligned
        *(bf16x8*)(xp + (size_t)idx*4 + 8) = o1;
        return;
    }

    int idx = (bid - PACK_B)*256 + threadIdx.x;
    if (idx < ED*ED*20) {
        // w2f: [(p*3+icb)*6+nt][lane][j], ic = icb*32+(lane>>4)*8+(j^sw)
        int j    = idx & 7;
        int lane = (idx >> 3) & 63;
        int grp  = idx >> 9;
        int nt   = grp % 6;
        int t    = grp / 6;
        int icb  = t % 3;
        int p    = t / 3;
        int sw   = (((p & 3) + icb) & 1) * 4;
        int oc = nt*16 + (lane & 15);
        int ic = icb*32 + (lane >> 4)*8 + (j ^ sw);
        w2f[idx] = (__bf16)w2[((size_t)(oc*ED + ic)*5 + (p >> 2))*4 + (p & 3)];
    } else if (idx < ED*ED*20 + 12*64*8) {
        // w1f: [grp=ks*6+ot][lane][j], A-frag value w1[oc][k]
        int i2   = idx - ED*ED*20;
        int j    = i2 & 7;
        int lane = (i2 >> 3) & 63;
        int grp  = i2 >> 9;
        int ks = grp / 6, ot = grp % 6;
        int oc = ot*16 + (lane & 15);
        int k  = ks*32 + (lane >> 4)*8 + j;
        w1f[i2] = (k < 60) ? (__bf16)w1[oc*60 + k] : (__bf16)0.0f;
    } else if (idx < ED*ED*20 + 12*64*8 + NBATCH*NR) {
        int i2 = idx - ED*ED*20 - 12*64*8;
        int b = i2 / NR, i = i2 % NR;
        float c0 = 0.2f + dist[b*4+0];
        float c1 = 0.2f + dist[b*4+1];
        float c2 = 0.2f + dist[b*4+2];
        float c3 = 0.2f + dist[b*4+3];
        float tmax = 0.5f * PI;
        float t  = tmax * ((float)i + 0.5f) / (float)NR;
        float t2 = t * t;
        float pt = t * (c0 + t2*(c1 + t2*(c2 + t2*c3)));
        float tm2 = tmax * tmax;
        float pm = tmax * (c0 + tm2*(c1 + tm2*(c2 + tm2*c3)));
        rtab[i2] = pt / pm * (0.5f * (float)IMGSZ);
    } else if (idx < ED*ED*20 + 12*64*8 + NBATCH*NR + NA) {
        int j = idx - ED*ED*20 - 12*64*8 - NBATCH*NR;
        float phi = 2.0f * PI * ((float)j + 0.5f) / (float)NA;
        costab[j] = cosf(phi) * SC;
        sintab[j] = sinf(phi) * SC;
    } else if (idx < PREP_N) {
        theta_out[idx - (ED*ED*20 + 12*64*8 + NBATCH*NR + NA)] = 0.5f * PI;
    }
}

// ---------------------------------------------------------------------------
// Mega kernel, WAVE-PRIVATE pipeline edition.  Counters (R0): 57% issue-idle,
// both pipes low, 16 waves/CU — all waves stalling TOGETHER on the same
// gather latency because 2 barriers/kr-iter kept them in lockstep (and
// launch-bounds experiments R6-R8 proved occupancy can't rise: reg demand
// ~105+ total, only (256,4) avoids spill).  Fix: remap work so the kr loop
// needs NO barriers, waves drift and cover each other's stalls.
//   - wave w owns output az a1 ≡ w (mod 4): pixel = l15*4 + w.  Then conv1
//     wave w writes exactly t1f kk = w*3..w*3+2 = what its conv2 (ka=w)
//     reads -> same-wave LDS RAW (lgkmcnt), barrier B deleted.
//   - lane (w,l) samples az col (l>>2)*16 + w*4 + (l&3), stored in a wave-
//     private 64-col slab (elem w*64+l, 8B-aligned reads) -> conv1 reads
//     only its own wave's samples, barrier A deleted.
//   - s_samp double-buffered (2 x 7680B) to break the cross-iteration WAR
//     (sample(kr+1) vs conv1(kr)).  LDS 39936B <= 40960 -> still 4
//     blocks/CU (registers bind at 4 regardless — this LDS was free).
// Barriers: 1 after w1f staging, 1 before reduction.  Zero in the loop.
// Loop body order: conv1 | conv2 | sched_barrier | sample(kr+1) — conv2's
// vmcnt waits never drain the sample gathers (in-order FIFO).
// ---------------------------------------------------------------------------
__global__ __launch_bounds__(256, 4)
void mega_kernel(const __bf16* __restrict__ xp,
                 const __bf16* __restrict__ w1f_g,
                 const __bf16* __restrict__ w2f,
                 const float* __restrict__ b1,
                 const float* __restrict__ b2,
                 const float* __restrict__ rtab,
                 const float* __restrict__ costab,
                 const float* __restrict__ sintab,
                 float* __restrict__ out) {
    __shared__ __attribute__((aligned(16))) char smem[39936];
    __bf16* s_samp0 = (__bf16*)smem;              // [15][256] 7680B
    __bf16* s_samp1 = (__bf16*)(smem + 7680);     // [15][256] 7680B
    __bf16* t1f     = (__bf16*)(smem + 15360);    // [12 kk][4 qT][16 m][8]
    __bf16* s_w1f   = (__bf16*)(smem + 27648);    // [12 grp][64 lane][8]
    float*  red     = (float*)smem;               // [3][16][98] f32 (aliases)

    int tid = threadIdx.x;
    int bid = blockIdx.x;                       // 2048
    int r2 = bid & 15;
    int aq = (bid >> 4) & 3;
    int b  = bid >> 6;
    int wave = tid >> 6, lane = tid & 63, l15 = lane & 15, quad = lane >> 4;

    // stage w1 fragments into LDS (12288 B, coalesced); barrier below
    #pragma unroll
    for (int i = 0; i < 3; ++i)
        *(bf16x8*)(s_w1f + i*2048 + tid*8) = *(const bf16x8*)(w1f_g + i*2048 + tid*8);

    // sampling az for this lane: wave-private mapping.  conv1 wave w lane
    // l15 computes a1 = l15*4+w, whose 4 k-az are cols l15*16 + w*4 + j —
    // sampled by lanes l15*4+j of wave w, stored at slab elem w*64 + lane.
    int col = ((lane >> 2) << 4) + wave*4 + (lane & 3);
    int az  = aq*256 + col;
    float sn = sintab[az];
    float cs = costab[az];
    int scol = wave*64 + lane;                  // storage slot (8B-aligned slabs)
    const __bf16* xpb = xp + (size_t)b*IMGSZ*IMGSZ*4;
    const float* rb = rtab + b*NR + r2*25;

    f32x4 acc2[6];
    #pragma unroll
    for (int nt = 0; nt < 6; ++nt) acc2[nt] = (f32x4){0.f,0.f,0.f,0.f};

    // sample 5 radius rows (kr) x 3 ch into a wave-private s_samp slab
    auto sample = [&](int kr, __bf16* sb) {
        #pragma unroll
        for (int q = 0; q < 5; ++q) {
            float r  = rb[kr*5 + q];                       // wave-uniform
            float gx = fmaf(r, sn, 111.5f);
            float gy = fmaf(r, cs, 111.5f);
            float x0f = floorf(gx), y0f = floorf(gy);
            float wx1 = gx - x0f, wx0 = 1.0f - wx1;
            float wy1 = gy - y0f, wy0 = 1.0f - wy1;
            int ix = (int)x0f, iy = (int)y0f;
            ix = min(max(ix, 0), IMGSZ-2);                 // always in-bounds
            iy = min(max(iy, 0), IMGSZ-2);
            const __bf16* img = xpb + ((size_t)iy*IMGSZ + ix)*4;
            bf16x8u p0 = *(const bf16x8u*)img;             // row y: cols x0,x1
            bf16x8u p1 = *(const bf16x8u*)(img + IMGSZ*4); // row y+1
            float w00 = wy0*wx0, w01 = wy0*wx1, w10 = wy1*wx0, w11 = wy1*wx1;
            #pragma unroll
            for (int c = 0; c < 3; ++c) {
                float v = w00*(float)p0[c] + w01*(float)p0[4+c]
                        + w10*(float)p1[c] + w11*(float)p1[4+c];
                sb[(c*5 + q)*SROW + scol] = (__bf16)v;
            }
        }
    };

    sample(0, s_samp0);
    __syncthreads();   // w1f staged (only cross-wave LDS dependency left)

    for (int kr = 0; kr < 5; ++kr) {
        __bf16* sb = (kr & 1) ? s_samp1 : s_samp0;

        // ---- conv1: a1 = l15*4 + wave; reads own wave's slab (no barrier)
        int cb = wave*64 + l15*4;
        f32x4 acc1[6];
        #pragma unroll
        for (int ot = 0; ot < 6; ++ot) acc1[ot] = (f32x4){0.f,0.f,0.f,0.f};

        frag_u fa, fb;
        fa.p.lo = *(const bf16x4a*)&sb[(quad*2    )*SROW + cb];
        fa.p.hi = *(const bf16x4a*)&sb[(quad*2 + 1)*SROW + cb];
        fb.p.lo = *(const bf16x4a*)&sb[(8 + quad*2)*SROW + cb];
        if (quad == 3) fb.p.hi = (bf16x4a){};
        else           fb.p.hi = *(const bf16x4a*)&sb[(9 + quad*2)*SROW + cb];

        #pragma unroll
        for (int ot = 0; ot < 6; ++ot) {
            bf16x8 wf0 = *(const bf16x8*)(s_w1f + (ot     )*512 + lane*8);
            bf16x8 wf1 = *(const bf16x8*)(s_w1f + (6 + ot )*512 + lane*8);
            acc1[ot] = __builtin_amdgcn_mfma_f32_16x16x32_bf16(wf0, fa.v, acc1[ot], 0, 0, 0);
            acc1[ot] = __builtin_amdgcn_mfma_f32_16x16x32_bf16(wf1, fb.v, acc1[ot], 0, 0, 0);
        }

        // epilogue: D col=l15 -> a1 = l15*4+wave: a2l = l15, ka = wave.
        // Writes land in t1f kk = wave*3.. — this wave's own conv2 region.
        #pragma unroll
        for (int ot = 0; ot < 6; ++ot) {
            f32x4 v = acc1[ot] + *(const f32x4*)(b1 + ot*16 + quad*4);
            bf16x4a wv;
            wv[0] = (__bf16)v[0]; wv[1] = (__bf16)v[1];
            wv[2] = (__bf16)v[2]; wv[3] = (__bf16)v[3];
            int icbase = ot*16 + quad*4;
            int kk = wave*3 + (icbase >> 5);
            int qT = (icbase >> 3) & 3;
            int jb = (icbase & 7) ^ ((kk & 1)*4);
            *(bf16x4a*)&t1f[((kk*4 + qT)*16 + l15)*8 + jb] = wv;
        }
        // no barrier: conv2 reads only this wave's t1f rows (lgkmcnt RAW)

        // ---- conv2: wave's ka = wave; 3 k-steps
        #pragma unroll
        for (int icb = 0; icb < 3; ++icb) {
            int kk = wave*3 + icb;
            int p  = kr*4 + wave;
            bf16x8 af = *(const bf16x8*)&t1f[(kk*64 + lane)*8];   // lane-contig
            const __bf16* wp = w2f + (size_t)((p*3 + icb)*6)*512 + lane*8;
            #pragma unroll
            for (int nt = 0; nt < 6; ++nt) {
                bf16x8 bf = *(const bf16x8*)(wp + nt*512);
                acc2[nt] = __builtin_amdgcn_mfma_f32_16x16x32_bf16(af, bf, acc2[nt], 0, 0, 0);
            }
        }

        // keep sample's gathers AFTER conv2's loads (vmcnt FIFO ordering)
        __builtin_amdgcn_sched_barrier(0);

        if (kr < 4) sample(kr + 1, (kr & 1) ? s_samp0 : s_samp1);
    }

    // ---- ka-quarter reduction (red aliases samp0/samp1/t1f-head; w1f safe)
    __syncthreads();
    if (wave) {
        float* rw = red + (wave - 1)*1568;     // 16*98
        #pragma unroll
        for (int nt = 0; nt < 6; ++nt)
            #pragma unroll
            for (int r = 0; r < 4; ++r)
                rw[(quad*4 + r)*98 + nt*16 + l15] = acc2[nt][r];
    }
    __syncthreads();
    if (wave == 0) {
        size_t ob = ((size_t)b*1024 + r2*64 + aq*16)*ED;
        #pragma unroll
        for (int nt = 0; nt < 6; ++nt) {
            int oc = nt*16 + l15;
            float bias = b2[oc];
            #pragma unroll
            for (int r = 0; r < 4; ++r) {
                int row = quad*4 + r;
                float v = acc2[nt][r] + bias
                        + red[row*98 + oc]
                        + red[1568 + row*98 + oc]
                        + red[3136 + row*98 + oc];
                out[ob + (size_t)row*ED + oc] = v;
            }
        }
    }
}

extern "C" void kernel_launch(void* const* d_in, const int* in_sizes, int n_in,
                              void* d_out, int out_size, void* d_ws, size_t ws_size,
                              hipStream_t stream) {
    const float* x    = (const float*)d_in[0];
    const float* dist = (const float*)d_in[1];
    const float* w1   = (const float*)d_in[2];
    const float* b1   = (const float*)d_in[3];
    const float* w2   = (const float*)d_in[4];
    const float* b2   = (const float*)d_in[5];
    float* out = (float*)d_out;

    float* rtab   = (float*)d_ws;                 // 12800 f32
    float* costab = rtab + NBATCH*NR;             // 1024 f32
    float* sintab = costab + NA;                  // 1024 f32
    __bf16* w2f   = (__bf16*)(sintab + NA);       // 184320 bf16
    __bf16* w1f   = w2f + ED*ED*20;               // 6144 bf16
    __bf16* xp    = w1f + 12*64*8;                // 32*224*224*4 bf16 (12.8MB)

    float* theta_out = out + (size_t)NBATCH*1024*ED;

    prep_pack_kernel<<<PACK_B + PREP_B, 256, 0, stream>>>(
        x, dist, w1, w2, xp, rtab, costab, sintab, w2f, w1f, theta_out);
    mega_kernel<<<NBATCH*16*4, 256, 0, stream>>>(
        xp, w1f, w2f, b1, b2, rtab, costab, sintab, out);
}